// Round 1
// baseline (1028.910 us; speedup 1.0000x reference)
//
#include <hip/hip_runtime.h>
#include <math.h>

// Problem constants (match reference)
#define BB 32
#define TT 2048
#define FF 2048
#define DQ 1024
#define UNITS 1024
#define HALF 1024          // F/2
#define CDIM 2048          // HALF + DQ
#define TC 16              // rows per WAVE chunk (wave-independent streaming)
#define NC (TT / TC)       // 128 chunks per batch

// Workspace layout (floats):
//   [0, 2048)                w = W1 @ V              (2048)
//   [2048]                   c0 = b1.V + bV          (1)
//   [2064, 2096)             qb[b]                   (32)
//   [4096, 69632)            raw scores              (B*T = 65536)
//   [69632, 73728)           m_c per chunk           (B*NC = 4096)
//   [73728, 77824)           l_c per chunk           (4096)
//   [81920, 81920+8388608)   ctx partials            (B*NC*F = 32 MiB)
// Total ~34 MiB.

// ---------------------------------------------------------------------------
// Kernel 0a: w[c] = sum_u W1[c,u] * V[u];  task 2048 computes c0 = b1.V + bV
// One wave per task.
__global__ void compute_w_kernel(const float* __restrict__ W1,
                                 const float* __restrict__ b1,
                                 const float* __restrict__ V,
                                 const float* __restrict__ bV,
                                 float* __restrict__ ws_w,
                                 float* __restrict__ ws_c0) {
    int g = blockIdx.x * 4 + (threadIdx.x >> 6);
    int lane = threadIdx.x & 63;
    if (g > CDIM) return;
    const float* src = (g < CDIM) ? (W1 + (size_t)g * UNITS) : b1;
    float acc = 0.f;
#pragma unroll
    for (int k = 0; k < UNITS / 256; ++k) {    // 4 iters, 64 lanes * 4 floats
        int idx = k * 256 + lane * 4;
        float4 a = *(const float4*)(src + idx);
        float4 v = *(const float4*)(V + idx);
        acc += a.x * v.x + a.y * v.y + a.z * v.z + a.w * v.w;
    }
#pragma unroll
    for (int off = 32; off >= 1; off >>= 1) acc += __shfl_down(acc, off, 64);
    if (lane == 0) {
        if (g < CDIM) ws_w[g] = acc;
        else          *ws_c0 = acc + bV[0];
    }
}

// ---------------------------------------------------------------------------
// Kernel 0b: qb[b] = query[b,:] . w[1024:2048] + c0.  One wave per b.
__global__ void compute_qb_kernel(const float* __restrict__ query,
                                  const float* __restrict__ ws_w,
                                  const float* __restrict__ ws_c0,
                                  float* __restrict__ ws_qb) {
    int g = blockIdx.x * 4 + (threadIdx.x >> 6);
    int lane = threadIdx.x & 63;
    if (g >= BB) return;
    const float* q = query + (size_t)g * DQ;
    const float* wq = ws_w + HALF;
    float acc = 0.f;
#pragma unroll
    for (int k = 0; k < DQ / 256; ++k) {
        int idx = k * 256 + lane * 4;
        float4 a = *(const float4*)(q + idx);
        float4 w = *(const float4*)(wq + idx);
        acc += a.x * w.x + a.y * w.y + a.z * w.z + a.w * w.w;
    }
#pragma unroll
    for (int off = 32; off >= 1; off >>= 1) acc += __shfl_down(acc, off, 64);
    if (lane == 0) ws_qb[g] = acc + *ws_c0;
}

// ---------------------------------------------------------------------------
// Kernel A (restructured): WAVE-independent streaming with online softmax.
// Each wave owns one (b, chunk) of TC=16 rows. Lane L owns columns
// f = j*256 + L*4 .. +3 for j=0..7 (full F=2048 across the wave).
// Key-half dot uses j=0..3 with a 6-step shfl_xor butterfly (broadcasts the
// sum to all lanes — no LDS, no __syncthreads anywhere in the hot loop).
// Explicit 2-row software pipeline keeps one full row in flight per wave.
__global__ __launch_bounds__(256, 3)
void attn_stream_kernel(const float* __restrict__ values,
                        const float* __restrict__ ws_w,
                        const float* __restrict__ ws_qb,
                        float* __restrict__ ws_scores,
                        float* __restrict__ ws_m,
                        float* __restrict__ ws_l,
                        float* __restrict__ ws_ctx) {
    const int lane = threadIdx.x & 63;
    const int wv   = threadIdx.x >> 6;
    const int g    = blockIdx.x * 4 + wv;        // 0 .. B*NC-1 (4096)
    const int b    = g >> 7;                     // / NC (NC=128)
    const int chunk= g & (NC - 1);
    const int t0   = chunk * TC;

    // per-lane w fragments (key half only)
    const float4 w0 = *(const float4*)(ws_w + 0 * 256 + lane * 4);
    const float4 w1 = *(const float4*)(ws_w + 1 * 256 + lane * 4);
    const float4 w2 = *(const float4*)(ws_w + 2 * 256 + lane * 4);
    const float4 w3 = *(const float4*)(ws_w + 3 * 256 + lane * 4);
    const float qb = ws_qb[b];

    const float* vbase = values + (size_t)b * TT * FF + (size_t)t0 * FF + lane * 4;

    float4 acc[8];
#pragma unroll
    for (int j = 0; j < 8; ++j) acc[j] = make_float4(0.f, 0.f, 0.f, 0.f);

    float m = -1e30f, l = 0.f, skeep = 0.f;

    float4 va[8], vb[8];
#pragma unroll
    for (int j = 0; j < 8; ++j) va[j] = *(const float4*)(vbase + j * 256);

    auto process = [&](const float4 (&v)[8], int ri) {
        float d = v[0].x * w0.x + v[0].y * w0.y + v[0].z * w0.z + v[0].w * w0.w
                + v[1].x * w1.x + v[1].y * w1.y + v[1].z * w1.z + v[1].w * w1.w
                + v[2].x * w2.x + v[2].y * w2.y + v[2].z * w2.z + v[2].w * w2.w
                + v[3].x * w3.x + v[3].y * w3.y + v[3].z * w3.z + v[3].w * w3.w;
#pragma unroll
        for (int off = 1; off <= 32; off <<= 1) d += __shfl_xor(d, off, 64);
        const float s = d + qb;
        skeep = (lane == ri) ? s : skeep;
        const float mn  = fmaxf(m, s);
        const float scl = __expf(m - mn);
        const float p   = __expf(s - mn);
        l = l * scl + p;
#pragma unroll
        for (int j = 0; j < 8; ++j) {
            acc[j].x = acc[j].x * scl + p * v[j].x;
            acc[j].y = acc[j].y * scl + p * v[j].y;
            acc[j].z = acc[j].z * scl + p * v[j].z;
            acc[j].w = acc[j].w * scl + p * v[j].w;
        }
        m = mn;
    };

#pragma unroll
    for (int r = 0; r < TC; r += 2) {
        const float* rb = vbase + (size_t)(r + 1) * FF;
#pragma unroll
        for (int j = 0; j < 8; ++j) vb[j] = *(const float4*)(rb + j * 256);
        process(va, r);
        if (r + 2 < TC) {
            const float* ra = vbase + (size_t)(r + 2) * FF;
#pragma unroll
            for (int j = 0; j < 8; ++j) va[j] = *(const float4*)(ra + j * 256);
        }
        process(vb, r + 1);
    }

    if (lane < TC) ws_scores[b * TT + t0 + lane] = skeep;
    if (lane == 0) { ws_m[g] = m; ws_l[g] = l; }
    float* cdst = ws_ctx + (size_t)g * FF + lane * 4;
#pragma unroll
    for (int j = 0; j < 8; ++j) *(float4*)(cdst + j * 256) = acc[j];
}

// ---------------------------------------------------------------------------
// Kernel B: per (b, seg) combine chunk partials, write attn weights + context.
// grid = B*8 blocks, 256 threads; seg covers 256 t-values and 256 f-columns.
__global__ void combine_kernel(const float* __restrict__ ws_scores,
                               const float* __restrict__ ws_m,
                               const float* __restrict__ ws_l,
                               const float* __restrict__ ws_ctx,
                               float* __restrict__ out) {
    const int b = blockIdx.x >> 3;
    const int seg = blockIdx.x & 7;
    const int tid = threadIdx.x;

    __shared__ float ms[NC], ls[NC], co[NC];
    for (int c = tid; c < NC; c += 256) {
        ms[c] = ws_m[b * NC + c];
        ls[c] = ws_l[b * NC + c];
    }
    __syncthreads();

    float mg = -1e30f;
#pragma unroll 8
    for (int c = 0; c < NC; ++c) mg = fmaxf(mg, ms[c]);
    float lg = 0.f;
#pragma unroll 8
    for (int c = 0; c < NC; ++c) lg += ls[c] * __expf(ms[c] - mg);
    const float inv = 1.0f / lg;

    for (int c = tid; c < NC; c += 256) co[c] = __expf(ms[c] - mg) * inv;
    __syncthreads();

    // attention weights: out[B*F + b*T + t], shape (B,T,1)
    const int t = seg * 256 + tid;
    out[BB * FF + b * TT + t] = __expf(ws_scores[b * TT + t] - mg) * inv;

    // context: out[b*F + f], shape (B,1,F)
    const int f = seg * 256 + tid;
    float acc = 0.f;
#pragma unroll 8
    for (int c = 0; c < NC; ++c) {
        acc += ws_ctx[(size_t)(b * NC + c) * FF + f] * co[c];
    }
    out[b * FF + f] = acc;
}

// ---------------------------------------------------------------------------
extern "C" void kernel_launch(void* const* d_in, const int* in_sizes, int n_in,
                              void* d_out, int out_size, void* d_ws, size_t ws_size,
                              hipStream_t stream) {
    const float* query  = (const float*)d_in[0];   // (32, 1024)
    const float* values = (const float*)d_in[1];   // (32, 2048, 2048)
    const float* W1     = (const float*)d_in[2];   // (2048, 1024)
    const float* b1     = (const float*)d_in[3];   // (1024,)
    const float* V      = (const float*)d_in[4];   // (1024, 1)
    const float* bV     = (const float*)d_in[5];   // (1,)
    float* out = (float*)d_out;                    // 65536 ctx + 65536 attn

    float* ws        = (float*)d_ws;
    float* ws_w      = ws;            // 2048
    float* ws_c0     = ws + 2048;     // 1
    float* ws_qb     = ws + 2064;     // 32
    float* ws_scores = ws + 4096;     // 65536
    float* ws_m      = ws + 69632;    // 4096
    float* ws_l      = ws + 73728;    // 4096
    float* ws_ctx    = ws + 81920;    // 8388608 (32 MiB)

    // 0a: w = W1 @ V, c0 = b1.V + bV  (2049 wave-tasks)
    compute_w_kernel<<<513, 256, 0, stream>>>(W1, b1, V, bV, ws_w, ws_c0);
    // 0b: qb[b] = query[b] . w[1024:] + c0  (32 wave-tasks)
    compute_qb_kernel<<<8, 256, 0, stream>>>(query, ws_w, ws_c0, ws_qb);
    // A: wave-independent single-pass stream with online softmax
    attn_stream_kernel<<<(BB * NC) / 4, 256, 0, stream>>>(values, ws_w, ws_qb,
                                                          ws_scores, ws_m, ws_l, ws_ctx);
    // B: combine chunk partials, write outputs
    combine_kernel<<<BB * 8, 256, 0, stream>>>(ws_scores, ws_m, ws_l, ws_ctx, out);
}